// Round 5
// baseline (409.420 us; speedup 1.0000x reference)
//
#include <hip/hip_runtime.h>
#include <hip/hip_fp16.h>
#include <math.h>

// R10: wave-local FFT — one frame pair per wave, zero barriers in the FFT.
// R9 showed latency/sync-bound (VALU 32%, HBM 17%, occupancy 38%): ~42
// __syncthreads per block with 4 waves in lockstep. Restructure: block = 4
// waves = 4 pairs; each wave owns a private 8KB LDS workspace and runs the
// whole 1024-pt FFT wave-synchronously (DS ops from one wave are processed
// in order; read-all-into-registers before write-all per pass; explicit
// lgkmcnt fences as insurance). Barriers/block: ~42 -> 3. Waves progress
// independently. Twiddles stay hoisted: k=(lane+64b)&(L-1) is b-independent
// for L<=64; L=256 rotates w_lane by e^{-i*pi*b/8} (compile-time constants).
// Zero frames (0,1028 unpaired) skip the FFT entirely.
// Carries R9: two-for-one real FFT + Hermitian untangle, tightened fixup
// predicate (|im|<TAU && re<TAU), poly atan2, f64 fixup, fp16 staging.
// x: (32,1,262144) fp32; basis: (1026,1,1024) fp32.
// out: mag (32,513,1029) ++ angle (32,513,1029) fp32 flat.

#define NFFT     1024
#define STRIDE_  256
#define CUTOFF_  513
#define NFRAMES  1029
#define BATCH_   32
#define XLEN     262144
#define FB       8            // frames per block (4 pairs = 4 waves)
#define TPB      256
#define NTILES   129          // ceil(1029/8)
#define RSTRIDE  (FB + 1)     // 9 (odd) -> conflict-free result buffer
#define QCAP     256          // expected ~12 used/block
#define TAU      0.05f
#define PI_F     3.14159265358979323846f
#define PIH_F    1.57079632679489661923f
#define TWO_PI   6.28318530717958647692f

// XOR bank swizzle: stride-1 stays free; strided pass-writes spread across banks.
__device__ __forceinline__ int sz(int i) { return i ^ ((i >> 5) & 31); }

__device__ __forceinline__ void lds_fence() {
    asm volatile("s_waitcnt lgkmcnt(0)" ::: "memory");
}

// Fast atan2: deg-7 minimax atan on [0,1] + quadrant logic. Max err ~1e-5 rad.
// mx==0 -> NaN, but such bins satisfy the queue predicate -> overwritten.
__device__ __forceinline__ float fast_atan2(float y, float x) {
    float ax = fabsf(x), ay = fabsf(y);
    float mx = fmaxf(ax, ay), mn = fminf(ax, ay);
    float a  = mn * __builtin_amdgcn_rcpf(mx);
    float s  = a * a;
    float r  = a * (0.9998660f + s * (-0.3302995f + s * (0.1801410f + s * (-0.0851330f))));
    if (ay > ax) r = PIH_F - r;
    if (x < 0.0f) r = PI_F - r;
    return copysignf(r, y);
}

// One wave-local radix-4 Stockham pass: 4 butterflies/lane (j = lane+64b),
// in place. All 16 complex inputs into registers, fence, compute+write, fence.
// cs,sn = accurate cos/sin of -2*pi*(lane&(L-1))/(4L) (base twiddle).
template<int L, int LOGL>
__device__ __forceinline__ void wfft_pass(float* __restrict__ aR, float* __restrict__ aI,
                                          int lane, float cs, float sn) {
    float c0r[4], c0i[4], c1r[4], c1i[4], c2r[4], c2i[4], c3r[4], c3i[4];
    #pragma unroll
    for (int b = 0; b < 4; ++b) {
        const int j = lane + 64 * b;
        const int i0 = sz(j), i1 = sz(j + 256), i2 = sz(j + 512), i3 = sz(j + 768);
        c0r[b] = aR[i0]; c0i[b] = aI[i0];
        c1r[b] = aR[i1]; c1i[b] = aI[i1];
        c2r[b] = aR[i2]; c2i[b] = aI[i2];
        c3r[b] = aR[i3]; c3i[b] = aI[i3];
    }
    lds_fence();   // all inputs secured before any in-place overwrite
    #pragma unroll
    for (int b = 0; b < 4; ++b) {
        const int j = lane + 64 * b;
        const int k = j & (L - 1);
        float csb = cs, snb = sn;
        if (L == 256) {
            // k = lane + 64b: w_k = w_lane * e^{-i*pi*b/8}
            const float cb[4] = {1.0f, 0.92387953251f, 0.70710678119f, 0.38268343236f};
            const float sb[4] = {0.0f, -0.38268343236f, -0.70710678119f, -0.92387953251f};
            csb = cs * cb[b] - sn * sb[b];
            snb = sn * cb[b] + cs * sb[b];
        }
        float C1r = c1r[b], C1i = c1i[b];
        float C2r = c2r[b], C2i = c2i[b];
        float C3r = c3r[b], C3i = c3i[b];
        {
            float w2r = csb * csb - snb * snb, w2i = 2.0f * csb * snb;
            float w3r = w2r * csb - w2i * snb, w3i = w2r * snb + w2i * csb;
            float t;
            t = C1r * csb - C1i * snb; C1i = C1r * snb + C1i * csb; C1r = t;
            t = C2r * w2r - C2i * w2i; C2i = C2r * w2i + C2i * w2r; C2r = t;
            t = C3r * w3r - C3i * w3i; C3i = C3r * w3i + C3i * w3r; C3r = t;
        }
        float d0r = c0r[b] + C2r, d0i = c0i[b] + C2i;
        float d1r = c0r[b] - C2r, d1i = c0i[b] - C2i;
        float d2r = C1r + C3r,   d2i = C1i + C3i;
        float d3r = C1i - C3i,   d3i = C3r - C1r;   // -i*(c1-c3)
        const int dbase = ((j >> LOGL) << (LOGL + 2)) | k;
        const int o0 = sz(dbase), o1 = sz(dbase + L), o2 = sz(dbase + 2 * L), o3 = sz(dbase + 3 * L);
        aR[o0] = d0r + d2r; aI[o0] = d0i + d2i;
        aR[o1] = d1r + d3r; aI[o1] = d1i + d3i;
        aR[o2] = d0r - d2r; aI[o2] = d0i - d2i;
        aR[o3] = d1r - d3r; aI[o3] = d1i - d3i;
    }
    lds_fence();   // writes drained before the next pass reads
}

__global__ __launch_bounds__(TPB, 3) void stft_fft_kernel(
    const float* __restrict__ x, const float* __restrict__ basis,
    float* __restrict__ out)
{
    __shared__ float aR[4][NFFT], aI[4][NFFT];   // 32 KB: 8 KB private per wave
    __shared__ __half resM[CUTOFF_ * RSTRIDE];   // 9.02 KB
    __shared__ __half resA[CUTOFF_ * RSTRIDE];   // 9.02 KB
    __shared__ unsigned queue[QCAP];             // 1 KB fixup worklist
    __shared__ int qn;

    const int tid  = threadIdx.x;
    const int wave = tid >> 6;
    const int lane = tid & 63;
    const int bx   = blockIdx.x;
    const int n    = bx / NTILES;
    const int tile = bx % NTILES;
    const int t0   = tile * FB;
    const int nt   = min(FB, NFRAMES - t0);
    const float* __restrict__ xb = x + (size_t)n * XLEN;

    if (tid == 0) qn = 0;

    // ---- per-lane hoisted constants: accurate twiddles + window (lane-only)
    float sn4, cs4, sn16, cs16, sn64, cs64, sn256, cs256;
    sincosf(-TWO_PI * (float)(lane & 3)  * (1.0f / 16.0f),   &sn4,   &cs4);
    sincosf(-TWO_PI * (float)(lane & 15) * (1.0f / 64.0f),   &sn16,  &cs16);
    sincosf(-TWO_PI * (float)lane        * (1.0f / 256.0f),  &sn64,  &cs64);
    sincosf(-TWO_PI * (float)lane        * (1.0f / 1024.0f), &sn256, &cs256);
    float wv[16];
    #pragma unroll
    for (int m = 0; m < 16; ++m)
        wv[m] = 0.5f - 0.5f * cosf((float)(lane + 64 * m) * (TWO_PI / NFFT));
    __syncthreads();   // qn visible to all waves

    // ---- one pair per wave, fully wave-local (no block barriers) ----
    const int fa  = 2 * wave;
    if (fa < nt) {
        const int fbv  = fa + 1;
        const bool hasB = (fbv < nt);
        const int baseA = (t0 + fa) * STRIDE_ - NFFT;
        // fully-OOB frame (true spectrum exactly 0): frames 0 and 1028 only
        const bool zeroA = (baseA + NFFT <= 0) || (baseA >= XLEN);
        float* __restrict__ wR = aR[wave];
        float* __restrict__ wI = aI[wave];

        if (!(zeroA && !hasB)) {
            // ---- fused: load + Hann + first radix-4 pass (L=1, k=0) ----
            #pragma unroll
            for (int b = 0; b < 4; ++b) {
                const int j = lane + 64 * b;
                float cr[4], ci[4];
                #pragma unroll
                for (int q = 0; q < 4; ++q) {
                    const int i = j + 256 * q;
                    const int pa = baseA + i;
                    const float w = wv[b + 4 * q];
                    float va = (pa >= 0 && pa < XLEN) ? xb[pa] : 0.0f;
                    const int pb = pa + STRIDE_;
                    float vb = (hasB && pb >= 0 && pb < XLEN) ? xb[pb] : 0.0f;
                    cr[q] = va * w;
                    ci[q] = vb * w;
                }
                float d0r = cr[0] + cr[2], d0i = ci[0] + ci[2];
                float d1r = cr[0] - cr[2], d1i = ci[0] - ci[2];
                float d2r = cr[1] + cr[3], d2i = ci[1] + ci[3];
                float d3r = ci[1] - ci[3], d3i = cr[3] - cr[1];   // -i*(c1-c3)
                const int dbase = j << 2;
                const int o0 = sz(dbase), o1 = sz(dbase + 1), o2 = sz(dbase + 2), o3 = sz(dbase + 3);
                wR[o0] = d0r + d2r; wI[o0] = d0i + d2i;
                wR[o1] = d1r + d3r; wI[o1] = d1i + d3i;
                wR[o2] = d0r - d2r; wI[o2] = d0i - d2i;
                wR[o3] = d1r - d3r; wI[o3] = d1i - d3i;
            }
            lds_fence();

            // ---- remaining 4 radix-4 Stockham passes ----
            wfft_pass<4,   2>(wR, wI, lane, cs4,   sn4);
            wfft_pass<16,  4>(wR, wI, lane, cs16,  sn16);
            wfft_pass<64,  6>(wR, wI, lane, cs64,  sn64);
            wfft_pass<256, 8>(wR, wI, lane, cs256, sn256);
        }

        // ---- epilogue (wave-local): untangle -> 2 frames; mag/angle fp16 ----
        for (int f = lane; f <= NFFT / 2; f += 64) {
            if (zeroA) {
                resM[f * RSTRIDE + fa] = __float2half(0.0f);
                resA[f * RSTRIDE + fa] = __float2half(0.0f);   // atan2(0,0)=0
            }
            if (!zeroA || hasB) {
                const int nf = (NFFT - f) & (NFFT - 1);
                float R0 = wR[sz(f)],  I0 = wI[sz(f)];
                float R1 = wR[sz(nf)], I1 = wI[sz(nf)];

                if (!zeroA) {
                    float reA = 0.5f * (R0 + R1), imA = 0.5f * (I0 - I1);
                    resM[f * RSTRIDE + fa] = __float2half(sqrtf(reA * reA + imA * imA));
                    resA[f * RSTRIDE + fa] = __float2half(fast_atan2(imA, reA));
                    if (fabsf(imA) < TAU && reA < TAU) {
                        int qi = atomicAdd(&qn, 1);
                        if (qi < QCAP)
                            queue[qi] = ((unsigned)fa << 16) | (unsigned)f;
                    }
                }
                if (hasB) {
                    float reB = 0.5f * (I0 + I1), imB = 0.5f * (R1 - R0);
                    resM[f * RSTRIDE + fbv] = __float2half(sqrtf(reB * reB + imB * imB));
                    resA[f * RSTRIDE + fbv] = __float2half(fast_atan2(imB, reB));
                    if (fabsf(imB) < TAU && reB < TAU) {
                        int qi = atomicAdd(&qn, 1);
                        if (qi < QCAP)
                            queue[qi] = ((unsigned)fbv << 16) | (unsigned)f;
                    }
                }
            }
        }
    }
    __syncthreads();   // all waves' results + queue visible

    // ---- f64 fixup: wave-cooperative dot with the ACTUAL fp32 basis rows ----
    {
        const int nq = min(qn, QCAP);
        for (int qi = wave; qi < nq; qi += TPB / 64) {
            unsigned e = queue[qi];
            int f  = (int)(e & 0xffffu);
            int ft = (int)(e >> 16);
            int base = (t0 + ft) * STRIDE_ - NFFT;
            const float* __restrict__ br = basis + (size_t)f * NFFT;
            const float* __restrict__ bi = basis + (size_t)(CUTOFF_ + f) * NFFT;
            double sr0 = 0.0, si0 = 0.0, sr1 = 0.0, si1 = 0.0;
            #pragma unroll 2
            for (int hh = lane; hh < NFFT; hh += 128) {
                int p0 = base + hh;
                int p1 = p0 + 64;
                if (p0 >= 0 && p0 < XLEN) {
                    double xv = (double)xb[p0];
                    sr0 += xv * (double)br[hh];
                    si0 += xv * (double)bi[hh];
                }
                if (p1 >= 0 && p1 < XLEN) {
                    double xv = (double)xb[p1];
                    sr1 += xv * (double)br[hh + 64];
                    si1 += xv * (double)bi[hh + 64];
                }
            }
            double sr = sr0 + sr1, si = si0 + si1;
            #pragma unroll
            for (int off = 32; off; off >>= 1) {
                sr += __shfl_down(sr, off);
                si += __shfl_down(si, off);
            }
            if (lane == 0) {
                float re = (float)sr, im = (float)si;
                resM[f * RSTRIDE + ft] = __float2half(sqrtf(re * re + im * im));
                resA[f * RSTRIDE + ft] = __float2half(atan2f(im, re));
            }
        }
    }
    __syncthreads();

    // ---- coalesced write-out: per frequency row, nt consecutive t ----
    const size_t magbase = (size_t)n * CUTOFF_ * NFRAMES;
    const size_t angoff  = (size_t)BATCH_ * CUTOFF_ * NFRAMES;
    for (int idx = tid; idx < CUTOFF_ * FB; idx += TPB) {
        int f  = idx >> 3;        // idx / FB
        int tt = idx & (FB - 1);  // idx % FB
        if (tt < nt) {
            size_t o = magbase + (size_t)f * NFRAMES + (size_t)(t0 + tt);
            out[o]          = __half2float(resM[f * RSTRIDE + tt]);
            out[angoff + o] = __half2float(resA[f * RSTRIDE + tt]);
        }
    }
}

extern "C" void kernel_launch(void* const* d_in, const int* in_sizes, int n_in,
                              void* d_out, int out_size, void* d_ws, size_t ws_size,
                              hipStream_t stream) {
    const float* x     = (const float*)d_in[0];
    const float* basis = (const float*)d_in[1];
    float* out = (float*)d_out;
    dim3 grid(BATCH_ * NTILES);
    dim3 block(TPB);
    stft_fft_kernel<<<grid, block, 0, stream>>>(x, basis, out);
}

// Round 6
// 374.989 us; speedup vs baseline: 1.0918x; 1.0918x over previous
//
#include <hip/hip_runtime.h>
#include <hip/hip_fp16.h>
#include <math.h>

// R11: register-resident FFT — no LDS workspace at all.
// R10 post-mortem: perf tracked occupancy (LDS-capacity-bound) and each
// Stockham pass was a ~120cy LDS round-trip chain. Fix both: four-step FFT
// 1024 = 16(in-register) x 64(cross-lane via shfl_xor).
//   lane l holds x[l + 64r], r=0..15 (coalesced loads)
//   step1: per-lane 16-pt DFT (2 radix-4 stages, compile-time W16 twiddles)
//   step2: twiddle e^{-2pi i l k2/1024} (chained powers of hoisted base)
//   step3: 64-pt cross-lane DIF radix-2, 6 shfl_xor stages (dist 32..1),
//          per-lane stage twiddles; lane l, reg k2 ends with X[k2+16*brev6(l)]
//   untangle partner X[N-k] = shfl_xor(reg 16-k2, 63); reg0 via computed lane.
// LDS 52.7KB -> 19.5KB (fp16 results+queue only). launch_bounds(256,4).
// Carries: two-for-one real FFT, Hermitian untangle, zero-frame direct store,
// tightened fixup predicate (|im|<TAU && re<TAU), poly atan2, f64 fixup.
// x: (32,1,262144) fp32; basis: (1026,1,1024) fp32.
// out: mag (32,513,1029) ++ angle (32,513,1029) fp32 flat.

#define NFFT     1024
#define STRIDE_  256
#define CUTOFF_  513
#define NFRAMES  1029
#define BATCH_   32
#define XLEN     262144
#define FB       8            // frames per block (4 pairs = 4 waves)
#define TPB      256
#define NTILES   129          // ceil(1029/8)
#define RSTRIDE  (FB + 1)     // 9 (odd) -> conflict-free result buffer
#define QCAP     256          // expected ~12 used/block
#define TAU      0.05f
#define PI_F     3.14159265358979323846f
#define PIH_F    1.57079632679489661923f
#define TWO_PI   6.28318530717958647692f

// Fast atan2: deg-7 minimax atan on [0,1] + quadrant logic. Max err ~1e-5 rad.
// mx==0 -> NaN, but such bins satisfy the queue predicate -> overwritten.
__device__ __forceinline__ float fast_atan2(float y, float x) {
    float ax = fabsf(x), ay = fabsf(y);
    float mx = fmaxf(ax, ay), mn = fminf(ax, ay);
    float a  = mn * __builtin_amdgcn_rcpf(mx);
    float s  = a * a;
    float r  = a * (0.9998660f + s * (-0.3302995f + s * (0.1801410f + s * (-0.0851330f))));
    if (ay > ax) r = PIH_F - r;
    if (x < 0.0f) r = PI_F - r;
    return copysignf(r, y);
}

// One cross-lane DIF radix-2 stage. Low lane: a+b. High lane: (b-a)*W.
// TC/TS are pre-baked per lane: (1,0) on low lanes, W_{2*DIST}^{lane&(DIST-1)} on high.
#define XSTAGE(DIST, TC, TS) do {                        \
    float br_ = __shfl_xor(ar, DIST, 64);                \
    float bi_ = __shfl_xor(ai, DIST, 64);                \
    float dr_ = (lane & DIST) ? (br_ - ar) : (ar + br_); \
    float di_ = (lane & DIST) ? (bi_ - ai) : (ai + bi_); \
    ar = dr_ * (TC) - di_ * (TS);                        \
    ai = dr_ * (TS) + di_ * (TC);                        \
} while (0)

__global__ __launch_bounds__(TPB, 4) void stft_fft_kernel(
    const float* __restrict__ x, const float* __restrict__ basis,
    float* __restrict__ out)
{
    __shared__ __half resM[CUTOFF_ * RSTRIDE];   // 9.02 KB
    __shared__ __half resA[CUTOFF_ * RSTRIDE];   // 9.02 KB
    __shared__ unsigned queue[QCAP];             // 1 KB fixup worklist
    __shared__ int qn;

    const int tid  = threadIdx.x;
    const int wave = tid >> 6;
    const int lane = tid & 63;
    const int bx   = blockIdx.x;
    const int n    = bx / NTILES;
    const int tile = bx % NTILES;
    const int t0   = tile * FB;
    const int nt   = min(FB, NFRAMES - t0);
    const float* __restrict__ xb = x + (size_t)n * XLEN;

    if (tid == 0) qn = 0;
    const int K1     = __brev((unsigned)lane) >> 26;               // bitrev6(lane)
    const int p0lane = __brev((unsigned)((64 - K1) & 63)) >> 26;   // partner lane for reg 0
    __syncthreads();   // qn visible

    const int fa = 2 * wave;
    if (fa < nt) {
        const int fbv   = fa + 1;
        const bool hasB = (fbv < nt);
        const int baseA = (t0 + fa) * STRIDE_ - NFFT;
        const bool zeroA = (baseA + NFFT <= 0) || (baseA >= XLEN);

        if (zeroA && !hasB) {
            // lone fully-OOB frame (1028): exact zeros, no FFT, no queue
            #pragma unroll
            for (int k2 = 0; k2 < 16; ++k2) {
                const int f = k2 + 16 * K1;
                if (f <= NFFT / 2) {
                    resM[f * RSTRIDE + fa] = __float2half(0.0f);
                    resA[f * RSTRIDE + fa] = __float2half(0.0f);
                }
            }
        } else {
            // ---- load + Hann window: lane l owns x[base + l + 64r] ----
            float yr[16], yi[16];
            #pragma unroll
            for (int r = 0; r < 16; ++r) {
                const int i = lane + 64 * r;
                const float w = 0.5f - 0.5f * cosf((float)i * (TWO_PI / NFFT));
                const int pa = baseA + i;
                float va = (pa >= 0 && pa < XLEN) ? xb[pa] : 0.0f;
                const int pb = pa + STRIDE_;
                float vb = (hasB && pb >= 0 && pb < XLEN) ? xb[pb] : 0.0f;
                yr[r] = va * w;
                yi[r] = vb * w;
            }

            // ---- step 1: in-lane 16-pt DFT, y_l[k2] = sum_r x_r W16^{r k2} ----
            float Ar[16], Ai[16];
            #pragma unroll
            for (int r0 = 0; r0 < 4; ++r0) {   // 4-pt DFT over r1 for each r0
                float q0r = yr[r0],      q0i = yi[r0];
                float q1r = yr[r0 + 4],  q1i = yi[r0 + 4];
                float q2r = yr[r0 + 8],  q2i = yi[r0 + 8];
                float q3r = yr[r0 + 12], q3i = yi[r0 + 12];
                float t0r = q0r + q2r, t0i = q0i + q2i;
                float t1r = q0r - q2r, t1i = q0i - q2i;
                float t2r = q1r + q3r, t2i = q1i + q3i;
                float t3r = q1i - q3i, t3i = q3r - q1r;   // -i*(q1-q3)
                Ar[4*r0+0] = t0r + t2r; Ai[4*r0+0] = t0i + t2i;
                Ar[4*r0+1] = t1r + t3r; Ai[4*r0+1] = t1i + t3i;
                Ar[4*r0+2] = t0r - t2r; Ai[4*r0+2] = t0i - t2i;
                Ar[4*r0+3] = t1r - t3r; Ai[4*r0+3] = t1i - t3i;
            }
            // W16^{r0*m} twiddle (compile-time constants), A indexed [4*r0+m]
            constexpr float TWC[16] = {
                1.f, 1.f, 1.f, 1.f,
                1.f,  0.92387953251128676f,  0.70710678118654752f,  0.38268343236508977f,
                1.f,  0.70710678118654752f,  0.f,                  -0.70710678118654752f,
                1.f,  0.38268343236508977f, -0.70710678118654752f, -0.92387953251128676f };
            constexpr float TWS[16] = {
                0.f, 0.f, 0.f, 0.f,
                0.f, -0.38268343236508977f, -0.70710678118654752f, -0.92387953251128676f,
                0.f, -0.70710678118654752f, -1.f,                  -0.70710678118654752f,
                0.f, -0.92387953251128676f, -0.70710678118654752f,  0.38268343236508977f };
            #pragma unroll
            for (int idx = 0; idx < 16; ++idx) {
                float tr = Ar[idx] * TWC[idx] - Ai[idx] * TWS[idx];
                Ai[idx]  = Ar[idx] * TWS[idx] + Ai[idx] * TWC[idx];
                Ar[idx]  = tr;
            }
            #pragma unroll
            for (int m = 0; m < 4; ++m) {      // 4-pt DFT over r0, y[m+4p]
                float q0r = Ar[m],      q0i = Ai[m];
                float q1r = Ar[4 + m],  q1i = Ai[4 + m];
                float q2r = Ar[8 + m],  q2i = Ai[8 + m];
                float q3r = Ar[12 + m], q3i = Ai[12 + m];
                float t0r = q0r + q2r, t0i = q0i + q2i;
                float t1r = q0r - q2r, t1i = q0i - q2i;
                float t2r = q1r + q3r, t2i = q1i + q3i;
                float t3r = q1i - q3i, t3i = q3r - q1r;
                yr[m + 0]  = t0r + t2r; yi[m + 0]  = t0i + t2i;
                yr[m + 4]  = t1r + t3r; yi[m + 4]  = t1i + t3i;
                yr[m + 8]  = t0r - t2r; yi[m + 8]  = t0i - t2i;
                yr[m + 12] = t1r - t3r; yi[m + 12] = t1i - t3i;
            }

            // ---- step 2: twiddle by e^{-2pi i l k2 / 1024}, chained powers ----
            float c1, s1;
            sincosf(-TWO_PI * (float)lane * (1.0f / 1024.0f), &s1, &c1);
            {
                float cc = 1.0f, ssv = 0.0f;
                #pragma unroll
                for (int k2 = 0; k2 < 16; ++k2) {
                    float tr = yr[k2] * cc - yi[k2] * ssv;
                    yi[k2]   = yr[k2] * ssv + yi[k2] * cc;
                    yr[k2]   = tr;
                    float nc = cc * c1 - ssv * s1;
                    ssv = cc * s1 + ssv * c1;
                    cc = nc;
                }
            }

            // ---- step 3: cross-lane 64-pt DIF radix-2, stage twiddles baked ----
            float tc32, ts32; sincosf(-TWO_PI * (float)(lane & 31) * (1.0f/64.0f), &ts32, &tc32);
            if (!(lane & 32)) { tc32 = 1.0f; ts32 = 0.0f; }
            float tc16, ts16; sincosf(-TWO_PI * (float)(lane & 15) * (1.0f/32.0f), &ts16, &tc16);
            if (!(lane & 16)) { tc16 = 1.0f; ts16 = 0.0f; }
            float tc8, ts8;   sincosf(-TWO_PI * (float)(lane & 7)  * (1.0f/16.0f), &ts8,  &tc8);
            if (!(lane & 8))  { tc8 = 1.0f; ts8 = 0.0f; }
            float tc4, ts4;   sincosf(-TWO_PI * (float)(lane & 3)  * (1.0f/8.0f),  &ts4,  &tc4);
            if (!(lane & 4))  { tc4 = 1.0f; ts4 = 0.0f; }
            float tc2 = 1.0f, ts2 = 0.0f;
            if ((lane & 2) && (lane & 1)) { tc2 = 0.0f; ts2 = -1.0f; }   // W4^1 = -i

            #pragma unroll
            for (int k2 = 0; k2 < 16; ++k2) {
                float ar = yr[k2], ai = yi[k2];
                XSTAGE(32, tc32, ts32);
                XSTAGE(16, tc16, ts16);
                XSTAGE(8,  tc8,  ts8);
                XSTAGE(4,  tc4,  ts4);
                XSTAGE(2,  tc2,  ts2);
                {   // dist 1: no twiddle
                    float br_ = __shfl_xor(ar, 1, 64);
                    float bi_ = __shfl_xor(ai, 1, 64);
                    float dr_ = (lane & 1) ? (br_ - ar) : (ar + br_);
                    float di_ = (lane & 1) ? (bi_ - ai) : (ai + bi_);
                    ar = dr_; ai = di_;
                }
                yr[k2] = ar; yi[k2] = ai;   // lane l, reg k2 = X[k2 + 16*brev6(l)]
            }

            // ---- untangle + mag/angle + fixup queue ----
            // X[N-k] for (k2,K1) lives at (reg 16-k2, lane 63-l); reg0 at p0lane.
            #pragma unroll
            for (int k2 = 0; k2 < 16; ++k2) {
                float prr, pii;
                if (k2 == 0) {
                    prr = __shfl(yr[0], p0lane, 64);
                    pii = __shfl(yi[0], p0lane, 64);
                } else {
                    prr = __shfl_xor(yr[16 - k2], 63, 64);
                    pii = __shfl_xor(yi[16 - k2], 63, 64);
                }
                const int f = k2 + 16 * K1;
                if (f <= NFFT / 2) {
                    const float R0 = yr[k2], I0 = yi[k2];
                    if (zeroA) {
                        resM[f * RSTRIDE + fa] = __float2half(0.0f);
                        resA[f * RSTRIDE + fa] = __float2half(0.0f);   // atan2(0,0)=0
                    } else {
                        float reA = 0.5f * (R0 + prr), imA = 0.5f * (I0 - pii);
                        resM[f * RSTRIDE + fa] = __float2half(sqrtf(reA * reA + imA * imA));
                        resA[f * RSTRIDE + fa] = __float2half(fast_atan2(imA, reA));
                        if (fabsf(imA) < TAU && reA < TAU) {
                            int qi = atomicAdd(&qn, 1);
                            if (qi < QCAP)
                                queue[qi] = ((unsigned)fa << 16) | (unsigned)f;
                        }
                    }
                    if (hasB) {
                        float reB = 0.5f * (I0 + pii), imB = 0.5f * (prr - R0);
                        resM[f * RSTRIDE + fbv] = __float2half(sqrtf(reB * reB + imB * imB));
                        resA[f * RSTRIDE + fbv] = __float2half(fast_atan2(imB, reB));
                        if (fabsf(imB) < TAU && reB < TAU) {
                            int qi = atomicAdd(&qn, 1);
                            if (qi < QCAP)
                                queue[qi] = ((unsigned)fbv << 16) | (unsigned)f;
                        }
                    }
                }
            }
        }
    }
    __syncthreads();   // all waves' results + queue visible

    // ---- f64 fixup: wave-cooperative dot with the ACTUAL fp32 basis rows ----
    {
        const int nq = min(qn, QCAP);
        for (int qi = wave; qi < nq; qi += TPB / 64) {
            unsigned e = queue[qi];
            int f  = (int)(e & 0xffffu);
            int ft = (int)(e >> 16);
            int base = (t0 + ft) * STRIDE_ - NFFT;
            const float* __restrict__ br = basis + (size_t)f * NFFT;
            const float* __restrict__ bi = basis + (size_t)(CUTOFF_ + f) * NFFT;
            double sr0 = 0.0, si0 = 0.0, sr1 = 0.0, si1 = 0.0;
            #pragma unroll 2
            for (int hh = lane; hh < NFFT; hh += 128) {
                int p0 = base + hh;
                int p1 = p0 + 64;
                if (p0 >= 0 && p0 < XLEN) {
                    double xv = (double)xb[p0];
                    sr0 += xv * (double)br[hh];
                    si0 += xv * (double)bi[hh];
                }
                if (p1 >= 0 && p1 < XLEN) {
                    double xv = (double)xb[p1];
                    sr1 += xv * (double)br[hh + 64];
                    si1 += xv * (double)bi[hh + 64];
                }
            }
            double sr = sr0 + sr1, si = si0 + si1;
            #pragma unroll
            for (int off = 32; off; off >>= 1) {
                sr += __shfl_down(sr, off);
                si += __shfl_down(si, off);
            }
            if (lane == 0) {
                float re = (float)sr, im = (float)si;
                resM[f * RSTRIDE + ft] = __float2half(sqrtf(re * re + im * im));
                resA[f * RSTRIDE + ft] = __float2half(atan2f(im, re));
            }
        }
    }
    __syncthreads();

    // ---- coalesced write-out: per frequency row, nt consecutive t ----
    const size_t magbase = (size_t)n * CUTOFF_ * NFRAMES;
    const size_t angoff  = (size_t)BATCH_ * CUTOFF_ * NFRAMES;
    for (int idx = tid; idx < CUTOFF_ * FB; idx += TPB) {
        int f  = idx >> 3;        // idx / FB
        int tt = idx & (FB - 1);  // idx % FB
        if (tt < nt) {
            size_t o = magbase + (size_t)f * NFRAMES + (size_t)(t0 + tt);
            out[o]          = __half2float(resM[f * RSTRIDE + tt]);
            out[angoff + o] = __half2float(resA[f * RSTRIDE + tt]);
        }
    }
}

extern "C" void kernel_launch(void* const* d_in, const int* in_sizes, int n_in,
                              void* d_out, int out_size, void* d_ws, size_t ws_size,
                              hipStream_t stream) {
    const float* x     = (const float*)d_in[0];
    const float* basis = (const float*)d_in[1];
    float* out = (float*)d_out;
    dim3 grid(BATCH_ * NTILES);
    dim3 block(TPB);
    stft_fft_kernel<<<grid, block, 0, stream>>>(x, basis, out);
}

// Round 7
// 360.000 us; speedup vs baseline: 1.1373x; 1.0416x over previous
//
#include <hip/hip_runtime.h>
#include <hip/hip_fp16.h>
#include <math.h>

// R12: R11 register-resident FFT with the three counter-driven fixes:
//  1) VGPR cap 64 -> 128 (launch_bounds(512,4)): R11's 16 independent
//     shfl-chains were serialized by the 64-reg cap (VGPR_Count=64 == cap).
//  2) hw __cosf/__sincosf for window + stage twiddles (R6's failure was the
//     queue flood, NOT hw-trans accuracy: eps 1e-5 * |X|~50 << TAU guard).
//     libm sincosf kept only for the step-2 chained base (x16 amplification).
//  3) FB 8 -> 16, TPB 256 -> 512: 8 pairs/block; output rows written as full
//     64B lines (WRITE_SIZE was 1.8x output = split-line amplification),
//     x halo re-fetch amortized over 2x frames.
// Four-step FFT unchanged (verified): 1024 = 16(in-reg) x 64(cross-lane),
// lane l holds x[l+64r]; step1 per-lane 16pt DFT; step2 twiddle W1024^(l*k2);
// step3 6x radix-2 shfl_xor DIF; lane l reg k2 = X[k2+16*brev6(l)];
// untangle partner via shfl_xor(reg 16-k2, 63).
// Carries: two-for-one real FFT, zero-frame direct store, tightened fixup
// predicate (|im|<TAU && re<TAU), poly atan2, f64 fixup, fp16 staging.
// x: (32,1,262144) fp32; basis: (1026,1,1024) fp32.
// out: mag (32,513,1029) ++ angle (32,513,1029) fp32 flat.

#define NFFT     1024
#define STRIDE_  256
#define CUTOFF_  513
#define NFRAMES  1029
#define BATCH_   32
#define XLEN     262144
#define FB       16           // frames per block (8 pairs = 8 waves)
#define TPB      512
#define NTILES   65           // ceil(1029/16)
#define RSTRIDE  (FB + 1)     // 17 (odd) -> conflict-spread result buffer
#define QCAP     256          // expected ~25 used/block
#define TAU      0.05f
#define PI_F     3.14159265358979323846f
#define PIH_F    1.57079632679489661923f
#define TWO_PI   6.28318530717958647692f

// Fast atan2: deg-7 minimax atan on [0,1] + quadrant logic. Max err ~1e-5 rad.
// mx==0 -> NaN, but such bins satisfy the queue predicate -> overwritten.
__device__ __forceinline__ float fast_atan2(float y, float x) {
    float ax = fabsf(x), ay = fabsf(y);
    float mx = fmaxf(ax, ay), mn = fminf(ax, ay);
    float a  = mn * __builtin_amdgcn_rcpf(mx);
    float s  = a * a;
    float r  = a * (0.9998660f + s * (-0.3302995f + s * (0.1801410f + s * (-0.0851330f))));
    if (ay > ax) r = PIH_F - r;
    if (x < 0.0f) r = PI_F - r;
    return copysignf(r, y);
}

// One cross-lane DIF radix-2 stage. Low lane: a+b. High lane: (b-a)*W.
// TC/TS are pre-baked per lane: (1,0) on low lanes, W_{2*DIST}^{lane&(DIST-1)} on high.
#define XSTAGE(DIST, TC, TS) do {                        \
    float br_ = __shfl_xor(ar, DIST, 64);                \
    float bi_ = __shfl_xor(ai, DIST, 64);                \
    float dr_ = (lane & DIST) ? (br_ - ar) : (ar + br_); \
    float di_ = (lane & DIST) ? (bi_ - ai) : (ai + bi_); \
    ar = dr_ * (TC) - di_ * (TS);                        \
    ai = dr_ * (TS) + di_ * (TC);                        \
} while (0)

__global__ __launch_bounds__(TPB, 4) void stft_fft_kernel(
    const float* __restrict__ x, const float* __restrict__ basis,
    float* __restrict__ out)
{
    __shared__ __half resM[CUTOFF_ * RSTRIDE];   // 17.4 KB
    __shared__ __half resA[CUTOFF_ * RSTRIDE];   // 17.4 KB
    __shared__ unsigned queue[QCAP];             // 1 KB fixup worklist
    __shared__ int qn;

    const int tid  = threadIdx.x;
    const int wave = tid >> 6;
    const int lane = tid & 63;
    const int bx   = blockIdx.x;
    const int n    = bx / NTILES;
    const int tile = bx % NTILES;
    const int t0   = tile * FB;
    const int nt   = min(FB, NFRAMES - t0);
    const float* __restrict__ xb = x + (size_t)n * XLEN;

    if (tid == 0) qn = 0;
    const int K1     = __brev((unsigned)lane) >> 26;               // bitrev6(lane)
    const int p0lane = __brev((unsigned)((64 - K1) & 63)) >> 26;   // partner lane for reg 0
    __syncthreads();   // qn visible

    const int fa = 2 * wave;
    if (fa < nt) {
        const int fbv   = fa + 1;
        const bool hasB = (fbv < nt);
        const int baseA = (t0 + fa) * STRIDE_ - NFFT;
        const bool zeroA = (baseA + NFFT <= 0) || (baseA >= XLEN);

        if (zeroA && !hasB) {
            // lone fully-OOB frame (1028): exact zeros, no FFT, no queue
            #pragma unroll
            for (int k2 = 0; k2 < 16; ++k2) {
                const int f = k2 + 16 * K1;
                if (f <= NFFT / 2) {
                    resM[f * RSTRIDE + fa] = __float2half(0.0f);
                    resA[f * RSTRIDE + fa] = __float2half(0.0f);
                }
            }
        } else {
            // ---- load + Hann window (hw cos): lane l owns x[base + l + 64r] ----
            float yr[16], yi[16];
            #pragma unroll
            for (int r = 0; r < 16; ++r) {
                const int i = lane + 64 * r;
                const float w = 0.5f - 0.5f * __cosf((float)i * (TWO_PI / NFFT));
                const int pa = baseA + i;
                float va = (pa >= 0 && pa < XLEN) ? xb[pa] : 0.0f;
                const int pb = pa + STRIDE_;
                float vb = (hasB && pb >= 0 && pb < XLEN) ? xb[pb] : 0.0f;
                yr[r] = va * w;
                yi[r] = vb * w;
            }

            // ---- step 1: in-lane 16-pt DFT, y_l[k2] = sum_r x_r W16^{r k2} ----
            float Ar[16], Ai[16];
            #pragma unroll
            for (int r0 = 0; r0 < 4; ++r0) {   // 4-pt DFT over r1 for each r0
                float q0r = yr[r0],      q0i = yi[r0];
                float q1r = yr[r0 + 4],  q1i = yi[r0 + 4];
                float q2r = yr[r0 + 8],  q2i = yi[r0 + 8];
                float q3r = yr[r0 + 12], q3i = yi[r0 + 12];
                float t0r = q0r + q2r, t0i = q0i + q2i;
                float t1r = q0r - q2r, t1i = q0i - q2i;
                float t2r = q1r + q3r, t2i = q1i + q3i;
                float t3r = q1i - q3i, t3i = q3r - q1r;   // -i*(q1-q3)
                Ar[4*r0+0] = t0r + t2r; Ai[4*r0+0] = t0i + t2i;
                Ar[4*r0+1] = t1r + t3r; Ai[4*r0+1] = t1i + t3i;
                Ar[4*r0+2] = t0r - t2r; Ai[4*r0+2] = t0i - t2i;
                Ar[4*r0+3] = t1r - t3r; Ai[4*r0+3] = t1i - t3i;
            }
            // W16^{r0*m} twiddle (compile-time constants), A indexed [4*r0+m]
            constexpr float TWC[16] = {
                1.f, 1.f, 1.f, 1.f,
                1.f,  0.92387953251128676f,  0.70710678118654752f,  0.38268343236508977f,
                1.f,  0.70710678118654752f,  0.f,                  -0.70710678118654752f,
                1.f,  0.38268343236508977f, -0.70710678118654752f, -0.92387953251128676f };
            constexpr float TWS[16] = {
                0.f, 0.f, 0.f, 0.f,
                0.f, -0.38268343236508977f, -0.70710678118654752f, -0.92387953251128676f,
                0.f, -0.70710678118654752f, -1.f,                  -0.70710678118654752f,
                0.f, -0.92387953251128676f, -0.70710678118654752f,  0.38268343236508977f };
            #pragma unroll
            for (int idx = 0; idx < 16; ++idx) {
                float tr = Ar[idx] * TWC[idx] - Ai[idx] * TWS[idx];
                Ai[idx]  = Ar[idx] * TWS[idx] + Ai[idx] * TWC[idx];
                Ar[idx]  = tr;
            }
            #pragma unroll
            for (int m = 0; m < 4; ++m) {      // 4-pt DFT over r0, y[m+4p]
                float q0r = Ar[m],      q0i = Ai[m];
                float q1r = Ar[4 + m],  q1i = Ai[4 + m];
                float q2r = Ar[8 + m],  q2i = Ai[8 + m];
                float q3r = Ar[12 + m], q3i = Ai[12 + m];
                float t0r = q0r + q2r, t0i = q0i + q2i;
                float t1r = q0r - q2r, t1i = q0i - q2i;
                float t2r = q1r + q3r, t2i = q1i + q3i;
                float t3r = q1i - q3i, t3i = q3r - q1r;
                yr[m + 0]  = t0r + t2r; yi[m + 0]  = t0i + t2i;
                yr[m + 4]  = t1r + t3r; yi[m + 4]  = t1i + t3i;
                yr[m + 8]  = t0r - t2r; yi[m + 8]  = t0i - t2i;
                yr[m + 12] = t1r - t3r; yi[m + 12] = t1i - t3i;
            }

            // ---- step 2: twiddle by e^{-2pi i l k2 / 1024}, chained powers ----
            // libm base (chained x16 amplifies error; hw 1e-5*16 would be marginal)
            float c1, s1;
            sincosf(-TWO_PI * (float)lane * (1.0f / 1024.0f), &s1, &c1);
            {
                float cc = 1.0f, ssv = 0.0f;
                #pragma unroll
                for (int k2 = 0; k2 < 16; ++k2) {
                    float tr = yr[k2] * cc - yi[k2] * ssv;
                    yi[k2]   = yr[k2] * ssv + yi[k2] * cc;
                    yr[k2]   = tr;
                    float nc = cc * c1 - ssv * s1;
                    ssv = cc * s1 + ssv * c1;
                    cc = nc;
                }
            }

            // ---- step 3: cross-lane 64-pt DIF radix-2, stage twiddles (hw) ----
            float tc32, ts32; __sincosf(-TWO_PI * (float)(lane & 31) * (1.0f/64.0f), &ts32, &tc32);
            if (!(lane & 32)) { tc32 = 1.0f; ts32 = 0.0f; }
            float tc16, ts16; __sincosf(-TWO_PI * (float)(lane & 15) * (1.0f/32.0f), &ts16, &tc16);
            if (!(lane & 16)) { tc16 = 1.0f; ts16 = 0.0f; }
            float tc8, ts8;   __sincosf(-TWO_PI * (float)(lane & 7)  * (1.0f/16.0f), &ts8,  &tc8);
            if (!(lane & 8))  { tc8 = 1.0f; ts8 = 0.0f; }
            float tc4, ts4;   __sincosf(-TWO_PI * (float)(lane & 3)  * (1.0f/8.0f),  &ts4,  &tc4);
            if (!(lane & 4))  { tc4 = 1.0f; ts4 = 0.0f; }
            float tc2 = 1.0f, ts2 = 0.0f;
            if ((lane & 2) && (lane & 1)) { tc2 = 0.0f; ts2 = -1.0f; }   // W4^1 = -i

            #pragma unroll
            for (int k2 = 0; k2 < 16; ++k2) {
                float ar = yr[k2], ai = yi[k2];
                XSTAGE(32, tc32, ts32);
                XSTAGE(16, tc16, ts16);
                XSTAGE(8,  tc8,  ts8);
                XSTAGE(4,  tc4,  ts4);
                XSTAGE(2,  tc2,  ts2);
                {   // dist 1: no twiddle
                    float br_ = __shfl_xor(ar, 1, 64);
                    float bi_ = __shfl_xor(ai, 1, 64);
                    float dr_ = (lane & 1) ? (br_ - ar) : (ar + br_);
                    float di_ = (lane & 1) ? (bi_ - ai) : (ai + bi_);
                    ar = dr_; ai = di_;
                }
                yr[k2] = ar; yi[k2] = ai;   // lane l, reg k2 = X[k2 + 16*brev6(l)]
            }

            // ---- untangle + mag/angle + fixup queue ----
            // X[N-k] for (k2,K1) lives at (reg 16-k2, lane 63-l); reg0 at p0lane.
            #pragma unroll
            for (int k2 = 0; k2 < 16; ++k2) {
                float prr, pii;
                if (k2 == 0) {
                    prr = __shfl(yr[0], p0lane, 64);
                    pii = __shfl(yi[0], p0lane, 64);
                } else {
                    prr = __shfl_xor(yr[16 - k2], 63, 64);
                    pii = __shfl_xor(yi[16 - k2], 63, 64);
                }
                const int f = k2 + 16 * K1;
                if (f <= NFFT / 2) {
                    const float R0 = yr[k2], I0 = yi[k2];
                    if (zeroA) {
                        resM[f * RSTRIDE + fa] = __float2half(0.0f);
                        resA[f * RSTRIDE + fa] = __float2half(0.0f);   // atan2(0,0)=0
                    } else {
                        float reA = 0.5f * (R0 + prr), imA = 0.5f * (I0 - pii);
                        resM[f * RSTRIDE + fa] = __float2half(sqrtf(reA * reA + imA * imA));
                        resA[f * RSTRIDE + fa] = __float2half(fast_atan2(imA, reA));
                        if (fabsf(imA) < TAU && reA < TAU) {
                            int qi = atomicAdd(&qn, 1);
                            if (qi < QCAP)
                                queue[qi] = ((unsigned)fa << 16) | (unsigned)f;
                        }
                    }
                    if (hasB) {
                        float reB = 0.5f * (I0 + pii), imB = 0.5f * (prr - R0);
                        resM[f * RSTRIDE + fbv] = __float2half(sqrtf(reB * reB + imB * imB));
                        resA[f * RSTRIDE + fbv] = __float2half(fast_atan2(imB, reB));
                        if (fabsf(imB) < TAU && reB < TAU) {
                            int qi = atomicAdd(&qn, 1);
                            if (qi < QCAP)
                                queue[qi] = ((unsigned)fbv << 16) | (unsigned)f;
                        }
                    }
                }
            }
        }
    }
    __syncthreads();   // all waves' results + queue visible

    // ---- f64 fixup: wave-cooperative dot with the ACTUAL fp32 basis rows ----
    {
        const int nq = min(qn, QCAP);
        for (int qi = wave; qi < nq; qi += TPB / 64) {
            unsigned e = queue[qi];
            int f  = (int)(e & 0xffffu);
            int ft = (int)(e >> 16);
            int base = (t0 + ft) * STRIDE_ - NFFT;
            const float* __restrict__ br = basis + (size_t)f * NFFT;
            const float* __restrict__ bi = basis + (size_t)(CUTOFF_ + f) * NFFT;
            double sr0 = 0.0, si0 = 0.0, sr1 = 0.0, si1 = 0.0;
            #pragma unroll 2
            for (int hh = lane; hh < NFFT; hh += 128) {
                int p0 = base + hh;
                int p1 = p0 + 64;
                if (p0 >= 0 && p0 < XLEN) {
                    double xv = (double)xb[p0];
                    sr0 += xv * (double)br[hh];
                    si0 += xv * (double)bi[hh];
                }
                if (p1 >= 0 && p1 < XLEN) {
                    double xv = (double)xb[p1];
                    sr1 += xv * (double)br[hh + 64];
                    si1 += xv * (double)bi[hh + 64];
                }
            }
            double sr = sr0 + sr1, si = si0 + si1;
            #pragma unroll
            for (int off = 32; off; off >>= 1) {
                sr += __shfl_down(sr, off);
                si += __shfl_down(si, off);
            }
            if (lane == 0) {
                float re = (float)sr, im = (float)si;
                resM[f * RSTRIDE + ft] = __float2half(sqrtf(re * re + im * im));
                resA[f * RSTRIDE + ft] = __float2half(atan2f(im, re));
            }
        }
    }
    __syncthreads();

    // ---- write-out: full 64B lines per f row (16 consecutive t) ----
    const size_t magbase = (size_t)n * CUTOFF_ * NFRAMES;
    const size_t angoff  = (size_t)BATCH_ * CUTOFF_ * NFRAMES;
    for (int idx = tid; idx < CUTOFF_ * FB; idx += TPB) {
        int f  = idx >> 4;        // idx / FB
        int tt = idx & (FB - 1);  // idx % FB
        if (tt < nt) {
            size_t o = magbase + (size_t)f * NFRAMES + (size_t)(t0 + tt);
            out[o]          = __half2float(resM[f * RSTRIDE + tt]);
            out[angoff + o] = __half2float(resA[f * RSTRIDE + tt]);
        }
    }
}

extern "C" void kernel_launch(void* const* d_in, const int* in_sizes, int n_in,
                              void* d_out, int out_size, void* d_ws, size_t ws_size,
                              hipStream_t stream) {
    const float* x     = (const float*)d_in[0];
    const float* basis = (const float*)d_in[1];
    float* out = (float*)d_out;
    dim3 grid(BATCH_ * NTILES);
    dim3 block(TPB);
    stft_fft_kernel<<<grid, block, 0, stream>>>(x, basis, out);
}

// Round 8
// 332.747 us; speedup vs baseline: 1.2304x; 1.0819x over previous
//
#include <hip/hip_runtime.h>
#include <hip/hip_fp16.h>
#include <math.h>

// R13: R12 + three counter-driven fixes:
//  1) KILL the 16-way result-store bank conflict (14.8M cycles ~ 9.5% of CU
//     time, unchanged since R11): stores hit f = k2+16*brev6(lane) -> lane
//     byte stride 544 = 136 dwords == 8 mod 32 -> 4 banks. Group padding
//     ridx(f,tt) = f*17 + (f>>4)*2 + tt -> stride 548B = 137 dwords == 9
//     mod 32, gcd(9,32)=1 -> all 32 banks, 2 lanes/bank = free.
//  2) x-load reuse: frame b's window = frame a's shifted by 256 samples =
//     4 chunks. Load 20 raw chunks, not 32 (-37% VMEM ops, -1/3 fetch).
//  3) One libm sincosf per pair: window w[r]=0.5-0.5cos(theta+r*pi/8)
//     expanded by angle-addition from (cos,sin)(theta) with compile-time
//     constants; step-2 base e^{-i theta} is the same values conjugated.
// Four-step FFT unchanged (verified): 1024 = 16(in-reg) x 64(cross-lane),
// lane l holds x[l+64r]; step1 per-lane 16pt DFT; step2 twiddle W1024^(l*k2);
// step3 6x radix-2 shfl_xor DIF; lane l reg k2 = X[k2+16*brev6(l)];
// untangle partner via shfl_xor(reg 16-k2, 63).
// Carries: two-for-one real FFT, zero-frame direct store, tightened fixup
// predicate (|im|<TAU && re<TAU), poly atan2, f64 fixup, fp16 staging.
// x: (32,1,262144) fp32; basis: (1026,1,1024) fp32.
// out: mag (32,513,1029) ++ angle (32,513,1029) fp32 flat.

#define NFFT     1024
#define STRIDE_  256
#define CUTOFF_  513
#define NFRAMES  1029
#define BATCH_   32
#define XLEN     262144
#define FB       16           // frames per block (8 pairs = 8 waves)
#define TPB      512
#define NTILES   65           // ceil(1029/16)
#define RSTRIDE  (FB + 1)     // 17
#define RESSZ    8800         // >= 512*17 + 32*2 + 15
#define QCAP     256          // expected ~25 used/block
#define TAU      0.05f
#define PI_F     3.14159265358979323846f
#define PIH_F    1.57079632679489661923f
#define TWO_PI   6.28318530717958647692f

// Group-padded result index: lane stride across f-groups = 548B = 137 dwords
// == 9 mod 32 -> conflict-free scatter (2 lanes/bank).
__device__ __forceinline__ int ridx(int f, int tt) {
    return f * RSTRIDE + ((f >> 4) << 1) + tt;
}

// Fast atan2: deg-7 minimax atan on [0,1] + quadrant logic. Max err ~1e-5 rad.
// mx==0 -> NaN, but such bins satisfy the queue predicate -> overwritten.
__device__ __forceinline__ float fast_atan2(float y, float x) {
    float ax = fabsf(x), ay = fabsf(y);
    float mx = fmaxf(ax, ay), mn = fminf(ax, ay);
    float a  = mn * __builtin_amdgcn_rcpf(mx);
    float s  = a * a;
    float r  = a * (0.9998660f + s * (-0.3302995f + s * (0.1801410f + s * (-0.0851330f))));
    if (ay > ax) r = PIH_F - r;
    if (x < 0.0f) r = PI_F - r;
    return copysignf(r, y);
}

// One cross-lane DIF radix-2 stage. Low lane: a+b. High lane: (b-a)*W.
#define XSTAGE(DIST, TC, TS) do {                        \
    float br_ = __shfl_xor(ar, DIST, 64);                \
    float bi_ = __shfl_xor(ai, DIST, 64);                \
    float dr_ = (lane & DIST) ? (br_ - ar) : (ar + br_); \
    float di_ = (lane & DIST) ? (bi_ - ai) : (ai + bi_); \
    ar = dr_ * (TC) - di_ * (TS);                        \
    ai = dr_ * (TS) + di_ * (TC);                        \
} while (0)

__global__ __launch_bounds__(TPB, 4) void stft_fft_kernel(
    const float* __restrict__ x, const float* __restrict__ basis,
    float* __restrict__ out)
{
    __shared__ __half resM[RESSZ];               // 17.2 KB (group-padded)
    __shared__ __half resA[RESSZ];               // 17.2 KB
    __shared__ unsigned queue[QCAP];             // 1 KB fixup worklist
    __shared__ int qn;

    const int tid  = threadIdx.x;
    const int wave = tid >> 6;
    const int lane = tid & 63;
    const int bx   = blockIdx.x;
    const int n    = bx / NTILES;
    const int tile = bx % NTILES;
    const int t0   = tile * FB;
    const int nt   = min(FB, NFRAMES - t0);
    const float* __restrict__ xb = x + (size_t)n * XLEN;

    if (tid == 0) qn = 0;
    const int K1     = __brev((unsigned)lane) >> 26;               // bitrev6(lane)
    const int p0lane = __brev((unsigned)((64 - K1) & 63)) >> 26;   // partner lane for reg 0
    __syncthreads();   // qn visible

    const int fa = 2 * wave;
    if (fa < nt) {
        const int fbv   = fa + 1;
        const bool hasB = (fbv < nt);
        const int baseA = (t0 + fa) * STRIDE_ - NFFT;
        const bool zeroA = (baseA + NFFT <= 0) || (baseA >= XLEN);

        if (zeroA && !hasB) {
            // lone fully-OOB frame (1028): exact zeros, no FFT, no queue
            #pragma unroll
            for (int k2 = 0; k2 < 16; ++k2) {
                const int f = k2 + 16 * K1;
                if (f <= NFFT / 2) {
                    resM[ridx(f, fa)] = __float2half(0.0f);
                    resA[ridx(f, fa)] = __float2half(0.0f);
                }
            }
        } else {
            // ---- one libm sincos per pair: theta = 2*pi*lane/1024 ----
            float sl, cl;
            sincosf(TWO_PI * (float)lane * (1.0f / 1024.0f), &sl, &cl);

            // ---- raw loads: 20 chunks cover frame a (r=0..15) AND frame b
            //      (b's chunk r = a's chunk r+4; 4 extra chunks r=16..19) ----
            float raw[20];
            #pragma unroll
            for (int r = 0; r < 20; ++r) {
                const int pa = baseA + lane + 64 * r;
                raw[r] = (pa >= 0 && pa < XLEN) ? xb[pa] : 0.0f;
            }

            // ---- window by angle-addition: w[r] = .5 - .5cos(theta + r*pi/8)
            constexpr float WC[16] = {   // cos(r*pi/8)
                1.f,  0.92387953251128676f,  0.70710678118654752f,  0.38268343236508977f,
                0.f, -0.38268343236508977f, -0.70710678118654752f, -0.92387953251128676f,
               -1.f, -0.92387953251128676f, -0.70710678118654752f, -0.38268343236508977f,
                0.f,  0.38268343236508977f,  0.70710678118654752f,  0.92387953251128676f };
            constexpr float WS[16] = {   // sin(r*pi/8)
                0.f,  0.38268343236508977f,  0.70710678118654752f,  0.92387953251128676f,
                1.f,  0.92387953251128676f,  0.70710678118654752f,  0.38268343236508977f,
                0.f, -0.38268343236508977f, -0.70710678118654752f, -0.92387953251128676f,
               -1.f, -0.92387953251128676f, -0.70710678118654752f, -0.38268343236508977f };
            const float hb = hasB ? 1.0f : 0.0f;
            float yr[16], yi[16];
            #pragma unroll
            for (int r = 0; r < 16; ++r) {
                const float w = 0.5f - 0.5f * (cl * WC[r] - sl * WS[r]);
                yr[r] = raw[r] * w;
                yi[r] = raw[r + 4] * w * hb;
            }

            // ---- step 1: in-lane 16-pt DFT, y_l[k2] = sum_r x_r W16^{r k2} ----
            float Ar[16], Ai[16];
            #pragma unroll
            for (int r0 = 0; r0 < 4; ++r0) {   // 4-pt DFT over r1 for each r0
                float q0r = yr[r0],      q0i = yi[r0];
                float q1r = yr[r0 + 4],  q1i = yi[r0 + 4];
                float q2r = yr[r0 + 8],  q2i = yi[r0 + 8];
                float q3r = yr[r0 + 12], q3i = yi[r0 + 12];
                float t0r = q0r + q2r, t0i = q0i + q2i;
                float t1r = q0r - q2r, t1i = q0i - q2i;
                float t2r = q1r + q3r, t2i = q1i + q3i;
                float t3r = q1i - q3i, t3i = q3r - q1r;   // -i*(q1-q3)
                Ar[4*r0+0] = t0r + t2r; Ai[4*r0+0] = t0i + t2i;
                Ar[4*r0+1] = t1r + t3r; Ai[4*r0+1] = t1i + t3i;
                Ar[4*r0+2] = t0r - t2r; Ai[4*r0+2] = t0i - t2i;
                Ar[4*r0+3] = t1r - t3r; Ai[4*r0+3] = t1i - t3i;
            }
            // W16^{r0*m} twiddle (compile-time constants), A indexed [4*r0+m]
            constexpr float TWC[16] = {
                1.f, 1.f, 1.f, 1.f,
                1.f,  0.92387953251128676f,  0.70710678118654752f,  0.38268343236508977f,
                1.f,  0.70710678118654752f,  0.f,                  -0.70710678118654752f,
                1.f,  0.38268343236508977f, -0.70710678118654752f, -0.92387953251128676f };
            constexpr float TWS[16] = {
                0.f, 0.f, 0.f, 0.f,
                0.f, -0.38268343236508977f, -0.70710678118654752f, -0.92387953251128676f,
                0.f, -0.70710678118654752f, -1.f,                  -0.70710678118654752f,
                0.f, -0.92387953251128676f, -0.70710678118654752f,  0.38268343236508977f };
            #pragma unroll
            for (int idx = 0; idx < 16; ++idx) {
                float tr = Ar[idx] * TWC[idx] - Ai[idx] * TWS[idx];
                Ai[idx]  = Ar[idx] * TWS[idx] + Ai[idx] * TWC[idx];
                Ar[idx]  = tr;
            }
            #pragma unroll
            for (int m = 0; m < 4; ++m) {      // 4-pt DFT over r0, y[m+4p]
                float q0r = Ar[m],      q0i = Ai[m];
                float q1r = Ar[4 + m],  q1i = Ai[4 + m];
                float q2r = Ar[8 + m],  q2i = Ai[8 + m];
                float q3r = Ar[12 + m], q3i = Ai[12 + m];
                float t0r = q0r + q2r, t0i = q0i + q2i;
                float t1r = q0r - q2r, t1i = q0i - q2i;
                float t2r = q1r + q3r, t2i = q1i + q3i;
                float t3r = q1i - q3i, t3i = q3r - q1r;
                yr[m + 0]  = t0r + t2r; yi[m + 0]  = t0i + t2i;
                yr[m + 4]  = t1r + t3r; yi[m + 4]  = t1i + t3i;
                yr[m + 8]  = t0r - t2r; yi[m + 8]  = t0i - t2i;
                yr[m + 12] = t1r - t3r; yi[m + 12] = t1i - t3i;
            }

            // ---- step 2: twiddle by e^{-2pi i l k2/1024} = (cl,-sl)^k2 chained
            {
                const float c1 = cl, s1 = -sl;
                float cc = 1.0f, ssv = 0.0f;
                #pragma unroll
                for (int k2 = 0; k2 < 16; ++k2) {
                    float tr = yr[k2] * cc - yi[k2] * ssv;
                    yi[k2]   = yr[k2] * ssv + yi[k2] * cc;
                    yr[k2]   = tr;
                    float nc = cc * c1 - ssv * s1;
                    ssv = cc * s1 + ssv * c1;
                    cc = nc;
                }
            }

            // ---- step 3: cross-lane 64-pt DIF radix-2, stage twiddles (hw) ----
            float tc32, ts32; __sincosf(-TWO_PI * (float)(lane & 31) * (1.0f/64.0f), &ts32, &tc32);
            if (!(lane & 32)) { tc32 = 1.0f; ts32 = 0.0f; }
            float tc16, ts16; __sincosf(-TWO_PI * (float)(lane & 15) * (1.0f/32.0f), &ts16, &tc16);
            if (!(lane & 16)) { tc16 = 1.0f; ts16 = 0.0f; }
            float tc8, ts8;   __sincosf(-TWO_PI * (float)(lane & 7)  * (1.0f/16.0f), &ts8,  &tc8);
            if (!(lane & 8))  { tc8 = 1.0f; ts8 = 0.0f; }
            float tc4, ts4;   __sincosf(-TWO_PI * (float)(lane & 3)  * (1.0f/8.0f),  &ts4,  &tc4);
            if (!(lane & 4))  { tc4 = 1.0f; ts4 = 0.0f; }
            float tc2 = 1.0f, ts2 = 0.0f;
            if ((lane & 2) && (lane & 1)) { tc2 = 0.0f; ts2 = -1.0f; }   // W4^1 = -i

            #pragma unroll
            for (int k2 = 0; k2 < 16; ++k2) {
                float ar = yr[k2], ai = yi[k2];
                XSTAGE(32, tc32, ts32);
                XSTAGE(16, tc16, ts16);
                XSTAGE(8,  tc8,  ts8);
                XSTAGE(4,  tc4,  ts4);
                XSTAGE(2,  tc2,  ts2);
                {   // dist 1: no twiddle
                    float br_ = __shfl_xor(ar, 1, 64);
                    float bi_ = __shfl_xor(ai, 1, 64);
                    float dr_ = (lane & 1) ? (br_ - ar) : (ar + br_);
                    float di_ = (lane & 1) ? (bi_ - ai) : (ai + bi_);
                    ar = dr_; ai = di_;
                }
                yr[k2] = ar; yi[k2] = ai;   // lane l, reg k2 = X[k2 + 16*brev6(l)]
            }

            // ---- untangle + mag/angle + fixup queue ----
            #pragma unroll
            for (int k2 = 0; k2 < 16; ++k2) {
                float prr, pii;
                if (k2 == 0) {
                    prr = __shfl(yr[0], p0lane, 64);
                    pii = __shfl(yi[0], p0lane, 64);
                } else {
                    prr = __shfl_xor(yr[16 - k2], 63, 64);
                    pii = __shfl_xor(yi[16 - k2], 63, 64);
                }
                const int f = k2 + 16 * K1;
                if (f <= NFFT / 2) {
                    const float R0 = yr[k2], I0 = yi[k2];
                    if (zeroA) {
                        resM[ridx(f, fa)] = __float2half(0.0f);
                        resA[ridx(f, fa)] = __float2half(0.0f);   // atan2(0,0)=0
                    } else {
                        float reA = 0.5f * (R0 + prr), imA = 0.5f * (I0 - pii);
                        resM[ridx(f, fa)] = __float2half(sqrtf(reA * reA + imA * imA));
                        resA[ridx(f, fa)] = __float2half(fast_atan2(imA, reA));
                        if (fabsf(imA) < TAU && reA < TAU) {
                            int qi = atomicAdd(&qn, 1);
                            if (qi < QCAP)
                                queue[qi] = ((unsigned)fa << 16) | (unsigned)f;
                        }
                    }
                    if (hasB) {
                        float reB = 0.5f * (I0 + pii), imB = 0.5f * (prr - R0);
                        resM[ridx(f, fbv)] = __float2half(sqrtf(reB * reB + imB * imB));
                        resA[ridx(f, fbv)] = __float2half(fast_atan2(imB, reB));
                        if (fabsf(imB) < TAU && reB < TAU) {
                            int qi = atomicAdd(&qn, 1);
                            if (qi < QCAP)
                                queue[qi] = ((unsigned)fbv << 16) | (unsigned)f;
                        }
                    }
                }
            }
        }
    }
    __syncthreads();   // all waves' results + queue visible

    // ---- f64 fixup: wave-cooperative dot with the ACTUAL fp32 basis rows ----
    {
        const int nq = min(qn, QCAP);
        for (int qi = wave; qi < nq; qi += TPB / 64) {
            unsigned e = queue[qi];
            int f  = (int)(e & 0xffffu);
            int ft = (int)(e >> 16);
            int base = (t0 + ft) * STRIDE_ - NFFT;
            const float* __restrict__ br = basis + (size_t)f * NFFT;
            const float* __restrict__ bi = basis + (size_t)(CUTOFF_ + f) * NFFT;
            double sr0 = 0.0, si0 = 0.0, sr1 = 0.0, si1 = 0.0;
            #pragma unroll 2
            for (int hh = lane; hh < NFFT; hh += 128) {
                int p0 = base + hh;
                int p1 = p0 + 64;
                if (p0 >= 0 && p0 < XLEN) {
                    double xv = (double)xb[p0];
                    sr0 += xv * (double)br[hh];
                    si0 += xv * (double)bi[hh];
                }
                if (p1 >= 0 && p1 < XLEN) {
                    double xv = (double)xb[p1];
                    sr1 += xv * (double)br[hh + 64];
                    si1 += xv * (double)bi[hh + 64];
                }
            }
            double sr = sr0 + sr1, si = si0 + si1;
            #pragma unroll
            for (int off = 32; off; off >>= 1) {
                sr += __shfl_down(sr, off);
                si += __shfl_down(si, off);
            }
            if (lane == 0) {
                float re = (float)sr, im = (float)si;
                resM[ridx(f, ft)] = __float2half(sqrtf(re * re + im * im));
                resA[ridx(f, ft)] = __float2half(atan2f(im, re));
            }
        }
    }
    __syncthreads();

    // ---- write-out: full 64B lines per f row (16 consecutive t) ----
    const size_t magbase = (size_t)n * CUTOFF_ * NFRAMES;
    const size_t angoff  = (size_t)BATCH_ * CUTOFF_ * NFRAMES;
    for (int idx = tid; idx < CUTOFF_ * FB; idx += TPB) {
        int f  = idx >> 4;        // idx / FB
        int tt = idx & (FB - 1);  // idx % FB
        if (tt < nt) {
            size_t o = magbase + (size_t)f * NFRAMES + (size_t)(t0 + tt);
            out[o]          = __half2float(resM[ridx(f, tt)]);
            out[angoff + o] = __half2float(resA[ridx(f, tt)]);
        }
    }
}

extern "C" void kernel_launch(void* const* d_in, const int* in_sizes, int n_in,
                              void* d_out, int out_size, void* d_ws, size_t ws_size,
                              hipStream_t stream) {
    const float* x     = (const float*)d_in[0];
    const float* basis = (const float*)d_in[1];
    float* out = (float*)d_out;
    dim3 grid(BATCH_ * NTILES);
    dim3 block(TPB);
    stft_fft_kernel<<<grid, block, 0, stream>>>(x, basis, out);
}